// Round 1
// 156.947 us; speedup vs baseline: 1.0322x; 1.0322x over previous
//
#include <hip/hip_runtime.h>
#include <stdint.h>

// Problem constants
constexpr int Bn = 4, Tn = 2048, En = 512, Dn = 768, Hn = 12, DHn = 64, Sn = 2560;

typedef __bf16 bf16x8 __attribute__((ext_vector_type(8)));
typedef float f32x4 __attribute__((ext_vector_type(4)));

#define MFMA16x16x32 __builtin_amdgcn_mfma_f32_16x16x32_bf16

// async global->LDS, 16B per lane. dst must be wave-uniform base (HW adds lane*16).
#define GLOAD_LDS16(g, l)                                                        \
  __builtin_amdgcn_global_load_lds((const __attribute__((address_space(1))) uint32_t*)(g), \
                                   (__attribute__((address_space(3))) uint32_t*)(l), 16, 0, 0)

// exp2-domain scale: 1/sqrt(64) * log2(e)
#define QSCALE 0.1803368843f
#define LOG2E  1.4426950409f

__device__ __forceinline__ unsigned short f2bf(float f) {
  union { float f; uint32_t u; } c;
  c.f = f;
  return (unsigned short)((c.u + 0x7fffu + ((c.u >> 16) & 1u)) >> 16);
}

// ---------------- fused prep: all fp32 -> bf16 conversions in ONE launch ----------------
__global__ __launch_bounds__(256) void prep_all(
    const float* __restrict__ tok, const float* __restrict__ ent,
    const float* __restrict__ qp, const float* __restrict__ mask,
    const float* __restrict__ w0, const float* __restrict__ w1, const float* __restrict__ w2,
    const float* __restrict__ w3, const float* __restrict__ w4, const float* __restrict__ w5,
    unsigned short* __restrict__ Xw, unsigned short* __restrict__ Xq,
    unsigned short* __restrict__ Xe, unsigned short* __restrict__ Wc,
    float* __restrict__ maskS)
{
  const int TOK4 = Bn * Tn * Dn / 4;
  const int ENT4 = Bn * En * Dn / 4;
  const int W4 = Dn * Dn / 4;
  int i = blockIdx.x * 256 + threadIdx.x;
  if (i < TOK4) {
    float4 v = ((const float4*)tok)[i];
    ushort4 o = { f2bf(v.x), f2bf(v.y), f2bf(v.z), f2bf(v.w) };
    ((ushort4*)Xw)[i] = o;
    return;
  }
  i -= TOK4;
  if (i < ENT4) {
    float4 e = ((const float4*)ent)[i];
    float4 q = ((const float4*)qp)[i];
    ushort4 p = { f2bf((e.x + q.x) * 0.5f), f2bf((e.y + q.y) * 0.5f),
                  f2bf((e.z + q.z) * 0.5f), f2bf((e.w + q.w) * 0.5f) };
    ushort4 x = { f2bf(e.x), f2bf(e.y), f2bf(e.z), f2bf(e.w) };
    ((ushort4*)Xq)[i] = p;
    ((ushort4*)Xe)[i] = x;
    return;
  }
  i -= ENT4;
  if (i < 6 * W4) {
    int wi = i / W4, off = i - wi * W4;
    const float* src = (wi == 0) ? w0 : (wi == 1) ? w1 : (wi == 2) ? w2
                     : (wi == 3) ? w3 : (wi == 4) ? w4 : w5;
    float4 v = ((const float4*)src)[off];
    ushort4 o = { f2bf(v.x), f2bf(v.y), f2bf(v.z), f2bf(v.w) };
    ((ushort4*)Wc)[i] = o;
    return;
  }
  i -= 6 * W4;
  {
    float4 v = ((const float4*)mask)[i];
    float4 o = { v.x * LOG2E, v.y * LOG2E, v.z * LOG2E, v.w * LOG2E };
    ((float4*)maskS)[i] = o;
  }
}

// ---------------- merged projection GEMM ----------------
// grid (80, 6, 3). bx<64: token rows (M=8192); bx>=64: entity rows (M=2048).
// z=0 -> Q (swapped C[n][s], pre-scaled QSCALE), z=1 -> K (swapped), z=2 -> Vt (transposed write).
__global__ __launch_bounds__(256, 2) void proj_gemm(
    const unsigned short* __restrict__ Xw_, const unsigned short* __restrict__ Xq_,
    const unsigned short* __restrict__ Xe_, const unsigned short* __restrict__ Wc,
    const float* __restrict__ b0, const float* __restrict__ b1, const float* __restrict__ b2,
    const float* __restrict__ b3, const float* __restrict__ b4, const float* __restrict__ b5,
    unsigned short* __restrict__ Qb, unsigned short* __restrict__ Kb, unsigned short* __restrict__ Vtb)
{
  const int z = blockIdx.z;
  const bool tokseg = (blockIdx.x < 64);
  const int m0 = tokseg ? blockIdx.x * 128 : (blockIdx.x - 64) * 128;
  const int widx = tokseg ? z : z + 3;
  const unsigned short* X = tokseg ? Xw_ : ((z == 2) ? Xe_ : Xq_);
  const unsigned short* W = Wc + (size_t)widx * Dn * Dn;
  const float* bias = (widx == 0) ? b0 : (widx == 1) ? b1 : (widx == 2) ? b2
                    : (widx == 3) ? b3 : (widx == 4) ? b4 : b5;
  const bool swap = (z != 2);
  const float oscale = (z == 0) ? QSCALE : 1.0f;
  const int batch = tokseg ? (m0 >> 11) : (m0 >> 9);
  const int sbase = tokseg ? (m0 & 2047) : (Tn + (m0 & 511));

  const int t = threadIdx.x;
  const int lane = t & 63, wave = t >> 6;
  const int l15 = lane & 15, g = lane >> 4;
  const int n0 = blockIdx.y * 128;

  __shared__ __align__(16) unsigned short ldsX[2][4096];  // [128][32]
  __shared__ __align__(16) unsigned short ldsW[2][4096];  // [128][32]

  f32x4 acc[4][4];
#pragma unroll
  for (int a = 0; a < 4; ++a)
#pragma unroll
    for (int b = 0; b < 4; ++b) acc[a][b] = (f32x4){0.f, 0.f, 0.f, 0.f};

  auto stage = [&](int buf, int k0) {
#pragma unroll
    for (int i = 0; i < 2; ++i) {
      int idx0 = i * 256 + wave * 64;
      int r = (idx0 + lane) >> 2;
      int ko = k0 + ((lane & 3) << 3);
      GLOAD_LDS16(X + (size_t)(m0 + r) * Dn + ko, &ldsX[buf][idx0 * 8]);
      GLOAD_LDS16(W + (size_t)(n0 + r) * Dn + ko, &ldsW[buf][idx0 * 8]);
    }
  };

  stage(0, 0);
  __syncthreads();

  const int aw = wave >> 1, bw = wave & 1;

  for (int ks = 0; ks < 24; ++ks) {
    int cur = ks & 1;
    if (ks < 23) stage(cur ^ 1, (ks + 1) * 32);
    const unsigned short* tX = ldsX[cur];
    const unsigned short* tW = ldsW[cur];
    const unsigned short* tA = swap ? tW : tX;
    const unsigned short* tB = swap ? tX : tW;
    bf16x8 af[4], bfr[4];
#pragma unroll
    for (int f = 0; f < 4; ++f) {
      int r = aw * 64 + f * 16 + l15;
      af[f] = *(const bf16x8*)(tA + r * 32 + (g << 3));
    }
#pragma unroll
    for (int f = 0; f < 4; ++f) {
      int r = bw * 64 + f * 16 + l15;
      bfr[f] = *(const bf16x8*)(tB + r * 32 + (g << 3));
    }
    __builtin_amdgcn_s_setprio(1);
#pragma unroll
    for (int mf = 0; mf < 4; ++mf)
#pragma unroll
      for (int nf = 0; nf < 4; ++nf)
        acc[mf][nf] = MFMA16x16x32(af[mf], bfr[nf], acc[mf][nf], 0, 0, 0);
    __builtin_amdgcn_s_setprio(0);
    __syncthreads();
  }

  if (swap) {
    unsigned short* outb = (z == 0) ? Qb : Kb;
#pragma unroll
    for (int mf = 0; mf < 4; ++mf) {
      int n = n0 + aw * 64 + mf * 16 + 4 * g;
      float4 b4 = *(const float4*)(bias + n);
      int h = n >> 6, dh0 = n & 63;
#pragma unroll
      for (int nf = 0; nf < 4; ++nf) {
        int s = sbase + bw * 64 + nf * 16 + l15;
        f32x4 a = acc[mf][nf];
        ushort4 o = { f2bf((a[0] + b4.x) * oscale), f2bf((a[1] + b4.y) * oscale),
                      f2bf((a[2] + b4.z) * oscale), f2bf((a[3] + b4.w) * oscale) };
        *(ushort4*)(outb + (((size_t)batch * Hn + h) * Sn + s) * DHn + dh0) = o;
      }
    }
  } else {
#pragma unroll
    for (int nf = 0; nf < 4; ++nf) {
      int n = n0 + bw * 64 + nf * 16 + l15;
      float bv = bias[n];
      int h = n >> 6, dh = n & 63;
      size_t vtrow = ((size_t)batch * Hn + h) * DHn + dh;
#pragma unroll
      for (int mf = 0; mf < 4; ++mf) {
        int s = sbase + aw * 64 + mf * 16 + 4 * g;
        f32x4 a = acc[mf][nf];
        ushort4 o = { f2bf(a[0] + bv), f2bf(a[1] + bv), f2bf(a[2] + bv), f2bf(a[3] + bv) };
        *(ushort4*)(Vtb + vtrow * Sn + s) = o;
      }
    }
  }
}

// ---------------- flash attention ----------------
// grid (20, 48) XCD-swizzled, 128 threads = 2 waves x 64 q rows (QBLK=128).
// Each wave owns 64 q rows (4 16-row subtiles) so the 16 KB K/V LDS chunk read
// is amortized over 2x the MFMA work vs the previous 4-wave/32-q layout: LDS
// pipe drops from co-dominant (~52 us) to ~28 us, leaving MFMA (~44 us) as the
// single dominant pipe. kv chunks of 64, double-buffered LDS K/V, one barrier
// per chunk, unroll x2. Swapped QK^T: C[kv][q], mask rides the MFMA C-operand.
// FIXED-BASELINE softmax: scores tightly bounded -> P = exp2(s) directly, no
// max tracking; baseline cancels in ctx/l. PV fully in-register via
// sigma-permuted V reads; row-sum l rides an all-ones A-fragment (ctxl).
__global__ __launch_bounds__(128, 2) void attn_kernel(
    const unsigned short* __restrict__ Qb, const unsigned short* __restrict__ Kb,
    const unsigned short* __restrict__ Vtb, const float* __restrict__ maskS,
    float* __restrict__ out)
{
  const int t = threadIdx.x, lane = t & 63, wave = t >> 6;
  const int l15 = lane & 15, g = lane >> 4;

  // XCD-aware swizzle: 960 blocks -> each XCD gets 120 contiguous (6 whole heads)
  const int bid = blockIdx.y * 20 + blockIdx.x;
  const int swz = (bid & 7) * 120 + (bid >> 3);
  const int bx = swz % 20, by = swz / 20;
  const int bb = by / Hn, h = by % Hn;
  const int qw = bx * 128 + wave * 64;   // 64 q rows per wave

  __shared__ __align__(16) unsigned short Klds[2][4096];   // [64 kv][64 dh], XOR-swizzled
  __shared__ __align__(16) unsigned short Vlds[2][4096];   // [64 dh][64 kv], XOR-swizzled

  const size_t headQ = ((size_t)bb * Hn + h) * Sn * DHn;
  const size_t headV = ((size_t)bb * Hn + h) * DHn * Sn;

  auto stage = [&](int buf, int c) {
    const int kv0 = c * 64;
#pragma unroll
    for (int i = 0; i < 4; ++i) {
      int idx0 = i * 128 + wave * 64;
      int r = (idx0 + lane) >> 3;
      int ssl = ((lane & 7) ^ (r & 7)) << 3;
      GLOAD_LDS16(Kb + headQ + (size_t)(kv0 + r) * DHn + ssl, &Klds[buf][idx0 * 8]);
      GLOAD_LDS16(Vtb + headV + (size_t)r * Sn + kv0 + ssl, &Vlds[buf][idx0 * 8]);
    }
  };

  // Q fragments held for whole KV loop; B-operand: lane holds Q[q=l15][dh=8g+j+32kq]
  bf16x8 qf[4][2];
#pragma unroll
  for (int i = 0; i < 4; ++i)
#pragma unroll
    for (int kq = 0; kq < 2; ++kq)
      qf[i][kq] = *(const bf16x8*)(Qb + headQ + (size_t)(qw + i * 16 + l15) * DHn + kq * 32 + g * 8);

  // Hoisted per-lane LDS byte offsets (within one buffer).
  const int l7 = l15 & 7;
  int koff[2], voff[2][2];
#pragma unroll
  for (int kq = 0; kq < 2; ++kq)
    koff[kq] = l15 * 128 + (((kq * 4 + g) ^ l7) << 4);
#pragma unroll
  for (int ksv = 0; ksv < 2; ++ksv)
#pragma unroll
    for (int hf = 0; hf < 2; ++hf)
      voff[ksv][hf] = l15 * 128 + (((4 * ksv + 2 * hf + (g >> 1)) ^ l7) << 4) + (g & 1) * 8;

  // all-ones A-fragment row (row 0 = the l-accumulator row)
  bf16x8 ones;
#pragma unroll
  for (int j = 0; j < 8; ++j) ones[j] = (l15 == 0) ? (__bf16)1.0f : (__bf16)0.0f;

  f32x4 ctx[4][4];
  f32x4 ctxl[4];
#pragma unroll
  for (int i = 0; i < 4; ++i) {
#pragma unroll
    for (int d = 0; d < 4; ++d) ctx[i][d] = (f32x4){0.f, 0.f, 0.f, 0.f};
    ctxl[i] = (f32x4){0.f, 0.f, 0.f, 0.f};
  }

  const char* KBp = (const char*)Klds;
  const char* VBp = (const char*)Vlds;
  const float* maskB = maskS + (size_t)bb * Sn;

  auto compute = [&](const int buf, const int c) {
    const int kv0 = c * 64;
    const char* KB = KBp + buf * 8192;
    const char* VB = VBp + buf * 8192;

    // mask (pre-scaled by log2e); lane owns kv = 16kvf+4g+r -> f32x4 C-init
    f32x4 mvv[4];
#pragma unroll
    for (int kvf = 0; kvf < 4; ++kvf) {
      float4 mv = *(const float4*)(maskB + kv0 + kvf * 16 + g * 4);
      mvv[kvf] = (f32x4){mv.x, mv.y, mv.z, mv.w};
    }

    // Two half-phases (ksv = kv halves of 32): QK^T -> P -> PV, keeping sacc
    // liveness scoped to one half (register budget: ~200 VGPR total).
#pragma unroll
    for (int ksv = 0; ksv < 2; ++ksv) {
      // QK^T: C[kv][q], mask rides C-in of the first MFMA of each chain
      f32x4 sacc[4][2];
#pragma unroll
      for (int kh = 0; kh < 2; ++kh) {
        const int kvf = 2 * ksv + kh;
        bf16x8 kf0 = *(const bf16x8*)(KB + kvf * 2048 + koff[0]);
        bf16x8 kf1 = *(const bf16x8*)(KB + kvf * 2048 + koff[1]);
        __builtin_amdgcn_s_setprio(1);
#pragma unroll
        for (int i = 0; i < 4; ++i) {
          f32x4 s0 = MFMA16x16x32(kf0, qf[i][0], mvv[kvf], 0, 0, 0);
          sacc[i][kh] = MFMA16x16x32(kf1, qf[i][1], s0, 0, 0, 0);
        }
        __builtin_amdgcn_s_setprio(0);
      }

      // fixed-baseline softmax: P = exp2(s) straight into PV B-fragments.
      // pb[i] elem j = P[kv=sigma(8g+j)][q=l15], sigma matches the permuted V read.
      bf16x8 pb[4];
#pragma unroll
      for (int i = 0; i < 4; ++i)
#pragma unroll
        for (int r = 0; r < 4; ++r) {
          pb[i][r]     = (__bf16)__builtin_amdgcn_exp2f(sacc[i][0][r]);
          pb[i][4 + r] = (__bf16)__builtin_amdgcn_exp2f(sacc[i][1][r]);
        }

      // PV: ctx^T[dh][q] += Vt x P ; V read sigma-permuted: A elem j = Vt[dh][sigma(8g+j)]
#pragma unroll
      for (int df = 0; df < 4; ++df) {
        union { uint64_t u[2]; bf16x8 v; } vv;
        vv.u[0] = *(const uint64_t*)(VB + df * 2048 + voff[ksv][0]);
        vv.u[1] = *(const uint64_t*)(VB + df * 2048 + voff[ksv][1]);
        __builtin_amdgcn_s_setprio(1);
#pragma unroll
        for (int i = 0; i < 4; ++i)
          ctx[i][df] = MFMA16x16x32(vv.v, pb[i], ctx[i][df], 0, 0, 0);
        __builtin_amdgcn_s_setprio(0);
      }
      // all-ones l-row: ctxl += 1 x P  (row-sum of P on the matrix pipe)
#pragma unroll
      for (int i = 0; i < 4; ++i)
        ctxl[i] = MFMA16x16x32(ones, pb[i], ctxl[i], 0, 0, 0);
    }
  };

  stage(0, 0);

  for (int c = 0; c < Sn / 64; c += 2) {
    __syncthreads();                    // chunk c staged; buf1 free
    stage(1, c + 1);
    compute(0, c);
    __syncthreads();                    // chunk c+1 staged; buf0 free
    if (c + 2 < Sn / 64) stage(0, c + 2);
    compute(1, c + 1);
  }

  // epilogue: ctx^T[dh][q] / l ; l lives in ctxl (row 0, lanes g==0, reg 0), col=q
#pragma unroll
  for (int i = 0; i < 4; ++i) {
    float lsum = __shfl(ctxl[i][0], l15);   // lane l15 holds col q=l15 (g=0, reg 0)
    float inv = 1.0f / lsum;
    int q = qw + i * 16 + l15;
    size_t rowoff;
    if (q < Tn) rowoff = ((size_t)bb * Tn + q) * Dn;
    else        rowoff = (size_t)Bn * Tn * Dn + ((size_t)bb * En + (q - Tn)) * Dn;
#pragma unroll
    for (int df = 0; df < 4; ++df) {
      int d = h * DHn + df * 16 + 4 * g;
      float4 o = { ctx[i][df][0] * inv, ctx[i][df][1] * inv, ctx[i][df][2] * inv, ctx[i][df][3] * inv };
      *(float4*)(out + rowoff + d) = o;
    }
  }
}

// ---------------- launcher ----------------
extern "C" void kernel_launch(void* const* d_in, const int* in_sizes, int n_in,
                              void* d_out, int out_size, void* d_ws, size_t ws_size,
                              hipStream_t stream) {
  (void)in_sizes; (void)n_in; (void)out_size; (void)ws_size;
  const float* tok  = (const float*)d_in[0];
  const float* ent  = (const float*)d_in[1];
  const float* mask = (const float*)d_in[2];
  const float* qpos = (const float*)d_in[3];
  const float* Wq = (const float*)d_in[4];  const float* bq = (const float*)d_in[5];
  const float* Wk = (const float*)d_in[6];  const float* bk = (const float*)d_in[7];
  const float* Wv = (const float*)d_in[8];  const float* bv = (const float*)d_in[9];
  const float* Weq = (const float*)d_in[10]; const float* beq = (const float*)d_in[11];
  const float* Wek = (const float*)d_in[12]; const float* bek = (const float*)d_in[13];
  const float* Wev = (const float*)d_in[14]; const float* bev = (const float*)d_in[15];
  float* out = (float*)d_out;

  unsigned short* ws = (unsigned short*)d_ws;
  const size_t headN = (size_t)Bn * Hn * Sn * DHn;  // 7,864,320
  unsigned short* Qb  = ws;
  unsigned short* Kb  = Qb + headN;
  unsigned short* Vtb = Kb + headN;
  unsigned short* Xw  = Vtb + headN;                 // [8192][768] bf16 token
  unsigned short* Xq  = Xw + (size_t)Bn * Tn * Dn;   // [2048][768] pae
  unsigned short* Xe  = Xq + (size_t)Bn * En * Dn;   // [2048][768] entity
  unsigned short* Wc  = Xe + (size_t)Bn * En * Dn;   // 6 x [768][768]
  float* maskS = (float*)(Wc + 6 * (size_t)Dn * Dn); // [B][S] scaled mask

  const int TOK4 = Bn * Tn * Dn / 4;
  const int ENT4 = Bn * En * Dn / 4;
  const int W4 = Dn * Dn / 4;
  const int MSK4 = Bn * Sn / 4;
  const int total4 = TOK4 + ENT4 + 6 * W4 + MSK4;
  prep_all<<<dim3((total4 + 255) / 256), 256, 0, stream>>>(
      tok, ent, qpos, mask, Wq, Wk, Wv, Weq, Wek, Wev, Xw, Xq, Xe, Wc, maskS);

  proj_gemm<<<dim3(80, Dn / 128, 3), 256, 0, stream>>>(
      Xw, Xq, Xe, Wc, bq, bk, bv, beq, bek, bev, Qb, Kb, Vtb);

  attn_kernel<<<dim3(Sn / 128, Bn * Hn), 128, 0, stream>>>(Qb, Kb, Vtb, maskS, out);
}